// Round 6
// baseline (305.982 us; speedup 1.0000x reference)
//
#include <hip/hip_runtime.h>
#include <cstdint>

// ---------- types & helpers ----------
typedef __attribute__((ext_vector_type(8))) short short8_t;
typedef __attribute__((ext_vector_type(8))) __bf16 bf16x8_t;
typedef __attribute__((ext_vector_type(4))) float f32x4_t;

__device__ __forceinline__ float bf2f(unsigned short u) {
  return __uint_as_float(((unsigned)u) << 16);
}
__device__ __forceinline__ unsigned short f2bf(float f) {  // RNE
  unsigned u = __float_as_uint(f);
  u += 0x7FFFu + ((u >> 16) & 1u);
  return (unsigned short)(u >> 16);
}
__device__ __forceinline__ unsigned short f2bf_rhu(float f) {  // round-half-up (hot loops)
  return (unsigned short)((__float_as_uint(f) + 0x8000u) >> 16);
}

// MFMA wrapper: tolerate either builtin signature (short8 or bf16x8 operands).
template <typename V>
__device__ __forceinline__ auto mfma16_impl(V a, V b, f32x4_t c, int)
    -> decltype(__builtin_amdgcn_mfma_f32_16x16x32_bf16(a, b, c, 0, 0, 0)) {
  return __builtin_amdgcn_mfma_f32_16x16x32_bf16(a, b, c, 0, 0, 0);
}
template <typename V>
__device__ __forceinline__ f32x4_t mfma16_impl(V a, V b, f32x4_t c, long) {
  bf16x8_t ab = __builtin_bit_cast(bf16x8_t, a);
  bf16x8_t bb = __builtin_bit_cast(bf16x8_t, b);
  return __builtin_amdgcn_mfma_f32_16x16x32_bf16(ab, bb, c, 0, 0, 0);
}
__device__ __forceinline__ f32x4_t MFMA16(short8_t a, short8_t b, f32x4_t c) {
  return mfma16_impl(a, b, c, 0);
}

#define SPITCH 136  // 128-elem rows padded to 136 (k_scores-verified, 0 conflicts)

// Wave/fragment ids for the 64x64-output 4-wave layout.
#define FRAG_VARS                                                       \
  const int tid = threadIdx.x;                                          \
  const int lane = tid & 63;                                            \
  const int wv = tid >> 6;                                              \
  const int mw = (wv >> 1) << 5;                                        \
  const int nw = (wv & 1) << 5;                                         \
  const int fr = lane & 15;                                             \
  const int fq = lane >> 4;                                             \
  f32x4_t acc00 = {0.f, 0.f, 0.f, 0.f};                                 \
  f32x4_t acc01 = acc00, acc10 = acc00, acc11 = acc00;

// Body sees: ml (local m), nl (local n), vv (float value). Variadic for commas.
#define GEMM_EPILOGUE(...)                                              \
  {                                                                     \
    const f32x4_t accs_[4] = {acc00, acc01, acc10, acc11};              \
    _Pragma("unroll") for (int im_ = 0; im_ < 2; ++im_)                 \
    _Pragma("unroll") for (int jn_ = 0; jn_ < 2; ++jn_) {               \
      f32x4_t aa_ = accs_[im_ * 2 + jn_];                               \
      const int ml0_ = mw + im_ * 16 + fq * 4;                          \
      const int nl = nw + jn_ * 16 + fr;                                \
      _Pragma("unroll") for (int r_ = 0; r_ < 4; ++r_) {                \
        const int ml = ml0_ + r_;                                       \
        const float vv = aa_[r_];                                       \
        __VA_ARGS__;                                                    \
      }                                                                 \
    }                                                                   \
  }

// bf16x8 (short8) * scalar f32 -> bf16x8
__device__ __forceinline__ short8_t prods8(short8_t t, float s) {
  union { short8_t v; unsigned short u[8]; } in, r;
  in.v = t;
#pragma unroll
  for (int j = 0; j < 8; ++j) r.u[j] = f2bf_rhu(bf2f(in.u[j]) * s);
  return r.v;
}

// ---------- dtype detector ----------
__global__ void k_detect(const void* q, int* flag) {
  const int t = threadIdx.x;  // 64 threads
  const unsigned short* p = (const unsigned short*)q;
  int w = 0;
  for (int i = t; i < 512; i += 64) {
    float v = bf2f(p[i]);
    float av = fabsf(v);
    if (!(av <= 1e4f) || (v != 0.f && av < 1e-10f)) ++w;  // NaN fails av<=1e4
  }
  for (int off = 32; off > 0; off >>= 1) w += __shfl_xor(w, off);
  if (t == 0) *flag = (w > 40) ? 1 : 0;  // 1 = inputs are f32
}

__device__ __forceinline__ unsigned short load_as_bf16(const void* p, size_t i, int f32mode) {
  return f32mode ? f2bf(((const float*)p)[i]) : ((const unsigned short*)p)[i];
}

// ---------- convert activations + biases to canonical bf16 ----------
struct ConvArgs {
  const void* src[9];
  unsigned short* dst[9];
  int n[9];
};

__global__ __launch_bounds__(256) void k_convert(ConvArgs a, const int* flag) {
  const int z = blockIdx.z;
  const int n = a.n[z];
  const int f32mode = *flag;
  const int stride = gridDim.x * blockDim.x;
  for (int i = blockIdx.x * blockDim.x + threadIdx.x; i < n; i += stride)
    a.dst[z][i] = load_as_bf16(a.src[z], i, f32mode);
}

// ---------- transpose all 6 weight matrices (K x 512 -> 512 x K) ----------
struct TransArgs {
  const void* src[6];
  unsigned short* dst[6];
  int K[6];
};

__global__ __launch_bounds__(256) void k_transpose(TransArgs args, const int* flag) {
  const int z = blockIdx.z;
  const int K = args.K[z];
  const int k0 = blockIdx.y * 32, n0 = blockIdx.x * 32;
  if (k0 >= K) return;
  const int f32mode = *flag;
  __shared__ unsigned short t[32][33];
  const int tx = threadIdx.x & 31, ty = threadIdx.x >> 5;
  const void* s = args.src[z];
#pragma unroll
  for (int i = 0; i < 4; ++i)
    t[ty + i * 8][tx] = load_as_bf16(s, (size_t)(k0 + ty + i * 8) * 512 + n0 + tx, f32mode);
  __syncthreads();
  unsigned short* d = args.dst[z];
#pragma unroll
  for (int i = 0; i < 4; ++i)
    d[(size_t)(n0 + ty + i * 8) * K + k0 + tx] = t[tx][ty + i * 8];
}

// ---------- five projections: 128-k chunks, reg-prefetch, LDS-staged ----------
struct ProjArgs {
  const unsigned short* A[5];
  const unsigned short* W[5];
  const unsigned short* bias[5];
  unsigned short* out[5];
};

__global__ __launch_bounds__(256) void k_proj(ProjArgs args) {
  const int op = blockIdx.z;
  const int by = blockIdx.y;
  if (op != 0 && by >= 16) return;
  const int m0 = by * 64, n0 = blockIdx.x * 64;
  FRAG_VARS;
  __shared__ __align__(16) unsigned short aL[64 * SPITCH];
  __shared__ __align__(16) unsigned short bL[64 * SPITCH];
  const unsigned short* A = args.A[op] + (size_t)m0 * 1024;
  const unsigned short* W = args.W[op] + (size_t)n0 * 1024;
  const int sr = tid >> 2;              // staging row 0..63
  const int sci = tid & 3;              // 4 uint4-chunks per row handled below
  uint4 pa[4], pb[4];
#pragma unroll
  for (int i = 0; i < 4; ++i) {
    const int u = tid + i * 256, r = u >> 4, c = (u & 15) * 8;
    pa[i] = *(const uint4*)&A[(size_t)r * 1024 + c];
    pb[i] = *(const uint4*)&W[(size_t)r * 1024 + c];
  }
  (void)sr; (void)sci;
  for (int kc = 0; kc < 8; ++kc) {
    __syncthreads();
#pragma unroll
    for (int i = 0; i < 4; ++i) {
      const int u = tid + i * 256, r = u >> 4, c = (u & 15) * 8;
      *(uint4*)&aL[r * SPITCH + c] = pa[i];
      *(uint4*)&bL[r * SPITCH + c] = pb[i];
    }
    __syncthreads();
    if (kc < 7) {
      const int kb = (kc + 1) * 128;
#pragma unroll
      for (int i = 0; i < 4; ++i) {
        const int u = tid + i * 256, r = u >> 4, c = (u & 15) * 8;
        pa[i] = *(const uint4*)&A[(size_t)r * 1024 + kb + c];
        pb[i] = *(const uint4*)&W[(size_t)r * 1024 + kb + c];
      }
    }
#pragma unroll
    for (int ks = 0; ks < 4; ++ks) {
      const int kf = ks * 32 + fq * 8;
      short8_t a0 = *(const short8_t*)&aL[(mw + fr) * SPITCH + kf];
      short8_t a1 = *(const short8_t*)&aL[(mw + 16 + fr) * SPITCH + kf];
      short8_t b0 = *(const short8_t*)&bL[(nw + fr) * SPITCH + kf];
      short8_t b1 = *(const short8_t*)&bL[(nw + 16 + fr) * SPITCH + kf];
      acc00 = MFMA16(a0, b0, acc00);
      acc01 = MFMA16(a0, b1, acc01);
      acc10 = MFMA16(a1, b0, acc10);
      acc11 = MFMA16(a1, b1, acc11);
    }
  }
  const float scale = (op == 0) ? 0.044194173824159216f : 1.0f;
  const unsigned short* bias = args.bias[op];
  unsigned short* out = args.out[op];
  GEMM_EPILOGUE({
    const float v = (vv + bf2f(bias[n0 + nl])) * scale;
    const int m = m0 + ml;
    const int n = n0 + nl;
    if (op < 3) {
      out[(size_t)m * 512 + n] = f2bf(v);
    } else {
      const int bb = m >> 6;
      const int ss = m & 63;
      out[(size_t)bb * 32768 + (size_t)n * 64 + ss] = f2bf(v);
    }
  });
}

// ---------- scores: reuse-heavy LDS-staged (R5 known-good) ----------
__global__ __launch_bounds__(256) void k_scores(
    const unsigned short* __restrict__ qs, const unsigned short* __restrict__ skey,
    const unsigned short* __restrict__ tkey, unsigned short* __restrict__ scores) {
  const int b = blockIdx.z;
  const int m0 = blockIdx.y * 64;
  const int sx = blockIdx.x;  // s = sx*2 + {0,1}
  const int tid = threadIdx.x;
  const int lane = tid & 63;
  const int wv = tid >> 6;
  const int mw = (wv >> 1) << 5;
  const int nw = (wv & 1) << 5;
  const int fr = lane & 15;
  const int fq = lane >> 4;
  __shared__ __align__(16) unsigned short qL[64 * SPITCH];
  __shared__ __align__(16) unsigned short tkL[64 * SPITCH];
  __shared__ __align__(16) unsigned short skL[2 * SPITCH];
  f32x4_t acc[2][4];
#pragma unroll
  for (int s = 0; s < 2; ++s)
#pragma unroll
    for (int i = 0; i < 4; ++i) acc[s][i] = (f32x4_t){0.f, 0.f, 0.f, 0.f};
  const unsigned short* qb = qs + ((size_t)b * 128 + m0) * 512;
  const unsigned short* tkb = tkey + (size_t)b * 64 * 512;
  const unsigned short* skb = skey + ((size_t)b * 64 + sx * 2) * 512;
  for (int kc = 0; kc < 4; ++kc) {
    const int kbase = kc * 128;
    __syncthreads();
#pragma unroll
    for (int i = 0; i < 4; ++i) {
      const int u = tid + i * 256;
      const int r = u >> 4, c = (u & 15) * 8;
      *(uint4*)&qL[r * SPITCH + c] = *(const uint4*)&qb[(size_t)r * 512 + kbase + c];
      *(uint4*)&tkL[r * SPITCH + c] = *(const uint4*)&tkb[(size_t)r * 512 + kbase + c];
    }
    if (tid < 32) {
      const int r = tid >> 4, c = (tid & 15) * 8;
      *(uint4*)&skL[r * SPITCH + c] = *(const uint4*)&skb[(size_t)r * 512 + kbase + c];
    }
    __syncthreads();
#pragma unroll
    for (int ks = 0; ks < 4; ++ks) {
      const int kf = ks * 32 + fq * 8;
      short8_t a0 = *(const short8_t*)&qL[(mw + fr) * SPITCH + kf];
      short8_t a1 = *(const short8_t*)&qL[(mw + 16 + fr) * SPITCH + kf];
      uint4 tq[2];
      tq[0] = *(const uint4*)&tkL[(nw + fr) * SPITCH + kf];
      tq[1] = *(const uint4*)&tkL[(nw + 16 + fr) * SPITCH + kf];
      float tlo[2][4], thi[2][4];
#pragma unroll
      for (int h = 0; h < 2; ++h) {
        const unsigned* tw = (const unsigned*)&tq[h];
#pragma unroll
        for (int j = 0; j < 4; ++j) {
          tlo[h][j] = __uint_as_float(tw[j] << 16);
          thi[h][j] = __uint_as_float(tw[j] & 0xffff0000u);
        }
      }
#pragma unroll
      for (int s = 0; s < 2; ++s) {
        uint4 skq = *(const uint4*)&skL[s * SPITCH + kf];
        const unsigned* sw = (const unsigned*)&skq;
        union { short8_t v; unsigned w[4]; } b0, b1;
#pragma unroll
        for (int j = 0; j < 4; ++j) {
          const float slo = __uint_as_float(sw[j] << 16);
          const float shi = __uint_as_float(sw[j] & 0xffff0000u);
          b0.w[j] = __builtin_amdgcn_perm(__float_as_uint(thi[0][j] * shi),
                                          __float_as_uint(tlo[0][j] * slo), 0x07060302);
          b1.w[j] = __builtin_amdgcn_perm(__float_as_uint(thi[1][j] * shi),
                                          __float_as_uint(tlo[1][j] * slo), 0x07060302);
        }
        acc[s][0] = MFMA16(a0, b0.v, acc[s][0]);
        acc[s][1] = MFMA16(a0, b1.v, acc[s][1]);
        acc[s][2] = MFMA16(a1, b0.v, acc[s][2]);
        acc[s][3] = MFMA16(a1, b1.v, acc[s][3]);
      }
    }
  }
#pragma unroll
  for (int s = 0; s < 2; ++s) {
    unsigned short* out = scores + ((size_t)b * 128 + m0) * 4096 + (size_t)(sx * 2 + s) * 64;
#pragma unroll
    for (int im = 0; im < 2; ++im)
#pragma unroll
      for (int jn = 0; jn < 2; ++jn) {
        f32x4_t aa = acc[s][im * 2 + jn];
        const int col = nw + jn * 16 + fr;
#pragma unroll
        for (int r = 0; r < 4; ++r) {
          const int row = mw + im * 16 + fq * 4 + r;
          out[(size_t)row * 4096 + col] = f2bf(aa[r]);
        }
      }
  }
}

// ---------- in-place softmax over each row of 4096 ----------
__global__ __launch_bounds__(256) void k_softmax(unsigned short* __restrict__ s) {
  unsigned short* p = s + (size_t)blockIdx.x * 4096;
  const int t = threadIdx.x;
  union U8 { uint4 q; unsigned short u[8]; };
  U8 a, b;
  a.q = *(const uint4*)&p[t * 16];
  b.q = *(const uint4*)&p[t * 16 + 8];
  float x[16];
#pragma unroll
  for (int j = 0; j < 8; ++j) { x[j] = bf2f(a.u[j]); x[8 + j] = bf2f(b.u[j]); }
  float m = x[0];
#pragma unroll
  for (int j = 1; j < 16; ++j) m = fmaxf(m, x[j]);
  for (int off = 32; off > 0; off >>= 1) m = fmaxf(m, __shfl_xor(m, off));
  __shared__ float redm[4], reds[4];
  if ((t & 63) == 0) redm[t >> 6] = m;
  __syncthreads();
  m = fmaxf(fmaxf(redm[0], redm[1]), fmaxf(redm[2], redm[3]));
  float sum = 0.f;
#pragma unroll
  for (int j = 0; j < 16; ++j) { x[j] = __expf(x[j] - m); sum += x[j]; }
  for (int off = 32; off > 0; off >>= 1) sum += __shfl_xor(sum, off);
  if ((t & 63) == 0) reds[t >> 6] = sum;
  __syncthreads();
  sum = reds[0] + reds[1] + reds[2] + reds[3];
  const float inv = 1.0f / sum;
#pragma unroll
  for (int j = 0; j < 8; ++j) {
    a.u[j] = f2bf(x[j] * inv);
    b.u[j] = f2bf(x[8 + j] * inv);
  }
  *(uint4*)&p[t * 16] = a.q;
  *(uint4*)&p[t * 16 + 8] = b.q;
}

// ---------- ctx partials: split-K x4 over s; bf16 partials ----------
__global__ __launch_bounds__(256) void k_ctx(
    const unsigned short* __restrict__ p, const unsigned short* __restrict__ svT,
    const unsigned short* __restrict__ tvT, unsigned short* __restrict__ part) {
  const int b = blockIdx.x >> 1;
  const int m0 = (blockIdx.x & 1) * 64;
  const int n0 = blockIdx.y * 64;
  const int z = blockIdx.z;
  FRAG_VARS;
  __shared__ __align__(16) unsigned short tvl[64 * 72];
  __shared__ __align__(16) unsigned short svl[64 * 24];
  {
    const unsigned short* tvb = tvT + (size_t)b * 32768 + (size_t)n0 * 64;
    const unsigned short* svb = svT + (size_t)b * 32768 + (size_t)n0 * 64 + z * 16;
#pragma unroll
    for (int it = 0; it < 2; ++it) {
      const int idx = tid + it * 256;
      const int r = idx >> 3, c = (idx & 7) * 8;
      *(uint4*)&tvl[r * 72 + c] = *(const uint4*)&tvb[(size_t)r * 64 + c];
    }
    if (tid < 128) {
      const int r = tid >> 1, c = (tid & 1) * 8;
      *(uint4*)&svl[r * 24 + c] = *(const uint4*)&svb[(size_t)r * 64 + c];
    }
  }
  __syncthreads();
  const unsigned short* ar0 =
      p + ((size_t)b * 128 + m0 + mw + fr) * 4096 + z * 1024 + fq * 8;
  const unsigned short* ar1 = ar0 + (size_t)16 * 4096;
  uint4 pa0[4], pa1[4];
#pragma unroll
  for (int i = 0; i < 4; ++i) {
    pa0[i] = *(const uint4*)(ar0 + i * 32);
    pa1[i] = *(const uint4*)(ar1 + i * 32);
  }
#pragma unroll 4
  for (int ks = 0; ks < 32; ++ks) {
    const int sl = ks & 3;
    short8_t av0 = __builtin_bit_cast(short8_t, pa0[sl]);
    short8_t av1 = __builtin_bit_cast(short8_t, pa1[sl]);
    const int kn = ks + 4;
    if (kn < 32) {
      pa0[sl] = *(const uint4*)(ar0 + kn * 32);
      pa1[sl] = *(const uint4*)(ar1 + kn * 32);
    }
    const int s_l = ks >> 1;
    const int t0 = (ks & 1) * 32;
    short8_t tv0 = *(const short8_t*)&tvl[(nw + fr) * 72 + t0 + fq * 8];
    short8_t tv1 = *(const short8_t*)&tvl[(nw + 16 + fr) * 72 + t0 + fq * 8];
    const float sv0 = bf2f(svl[(nw + fr) * 24 + s_l]);
    const float sv1 = bf2f(svl[(nw + 16 + fr) * 24 + s_l]);
    short8_t bv0 = prods8(tv0, sv0);
    short8_t bv1 = prods8(tv1, sv1);
    acc00 = MFMA16(av0, bv0, acc00);
    acc01 = MFMA16(av0, bv1, acc01);
    acc10 = MFMA16(av1, bv0, acc10);
    acc11 = MFMA16(av1, bv1, acc11);
  }
  unsigned short* out = part + ((size_t)z * 2048 + (size_t)b * 128 + m0) * 512 + n0;
  GEMM_EPILOGUE({ out[(size_t)ml * 512 + nl] = f2bf(vv); });
}

// ---------- reduce 4 bf16 partials -> bf16 ctx ----------
__global__ __launch_bounds__(256) void k_reduce(const unsigned short* __restrict__ part,
                                                unsigned short* __restrict__ ctx) {
  const size_t N = (size_t)2048 * 512;
  const size_t i = ((size_t)blockIdx.x * 256 + threadIdx.x) * 8;
  float s[8];
#pragma unroll
  for (int j = 0; j < 8; ++j) s[j] = 0.f;
#pragma unroll
  for (int z = 0; z < 4; ++z) {
    union { uint4 q; unsigned short u[8]; } t;
    t.q = *(const uint4*)&part[z * N + i];
#pragma unroll
    for (int j = 0; j < 8; ++j) s[j] += bf2f(t.u[j]);
  }
  union { uint4 q; unsigned short u[8]; } o;
#pragma unroll
  for (int j = 0; j < 8; ++j) o.u[j] = f2bf(s[j]);
  *(uint4*)&ctx[i] = o.q;
}

// ---------- out = relu(concat(query, ctx) @ Wo + bo): 128-k chunks, prefetch ----------
__global__ __launch_bounds__(256) void k_out(
    const unsigned short* __restrict__ query, const unsigned short* __restrict__ ctx,
    const unsigned short* __restrict__ WoT, const unsigned short* __restrict__ bo,
    void* __restrict__ outv, const int* __restrict__ flag) {
  const int m0 = blockIdx.y * 64, n0 = blockIdx.x * 64;
  const int f32mode = *flag;
  FRAG_VARS;
  __shared__ __align__(16) unsigned short aL[64 * SPITCH];
  __shared__ __align__(16) unsigned short bL[64 * SPITCH];
  const unsigned short* Q = query + (size_t)m0 * 1024;
  const unsigned short* C = ctx + (size_t)m0 * 512;
  const unsigned short* W = WoT + (size_t)n0 * 1536;
  uint4 pa[4], pb[4];
#pragma unroll
  for (int i = 0; i < 4; ++i) {
    const int u = tid + i * 256, r = u >> 4, c = (u & 15) * 8;
    pa[i] = *(const uint4*)&Q[(size_t)r * 1024 + c];
    pb[i] = *(const uint4*)&W[(size_t)r * 1536 + c];
  }
  for (int kc = 0; kc < 12; ++kc) {
    __syncthreads();
#pragma unroll
    for (int i = 0; i < 4; ++i) {
      const int u = tid + i * 256, r = u >> 4, c = (u & 15) * 8;
      *(uint4*)&aL[r * SPITCH + c] = pa[i];
      *(uint4*)&bL[r * SPITCH + c] = pb[i];
    }
    __syncthreads();
    if (kc < 11) {
      const int kb = (kc + 1) * 128;
#pragma unroll
      for (int i = 0; i < 4; ++i) {
        const int u = tid + i * 256, r = u >> 4, c = (u & 15) * 8;
        pa[i] = (kb < 1024) ? *(const uint4*)&Q[(size_t)r * 1024 + kb + c]
                            : *(const uint4*)&C[(size_t)r * 512 + (kb - 1024) + c];
        pb[i] = *(const uint4*)&W[(size_t)r * 1536 + kb + c];
      }
    }
#pragma unroll
    for (int ks = 0; ks < 4; ++ks) {
      const int kf = ks * 32 + fq * 8;
      short8_t a0 = *(const short8_t*)&aL[(mw + fr) * SPITCH + kf];
      short8_t a1 = *(const short8_t*)&aL[(mw + 16 + fr) * SPITCH + kf];
      short8_t b0 = *(const short8_t*)&bL[(nw + fr) * SPITCH + kf];
      short8_t b1 = *(const short8_t*)&bL[(nw + 16 + fr) * SPITCH + kf];
      acc00 = MFMA16(a0, b0, acc00);
      acc01 = MFMA16(a0, b1, acc01);
      acc10 = MFMA16(a1, b0, acc10);
      acc11 = MFMA16(a1, b1, acc11);
    }
  }
  GEMM_EPILOGUE({
    float v = fmaxf(vv + bf2f(bo[n0 + nl]), 0.f);
    const size_t idx = (size_t)(m0 + ml) * 512 + n0 + nl;
    if (f32mode)
      ((float*)outv)[idx] = v;
    else
      ((unsigned short*)outv)[idx] = f2bf(v);
  });
}

// ---------- launch ----------
extern "C" void kernel_launch(void* const* d_in, const int* in_sizes, int n_in,
                              void* d_out, int out_size, void* d_ws, size_t ws_size,
                              hipStream_t stream) {
  const void* query = d_in[0];
  const void* src = d_in[1];
  const void* trg = d_in[2];
  const void* Wq = d_in[3];
  const void* bq = d_in[4];
  const void* Ws = d_in[5];
  const void* bs = d_in[6];
  const void* Wt = d_in[7];
  const void* bt = d_in[8];
  const void* Wsv = d_in[9];
  const void* bsv = d_in[10];
  const void* Wtv = d_in[11];
  const void* btv = d_in[12];
  const void* Wo = d_in[13];
  const void* bo = d_in[14];

  char* ws = (char*)d_ws;
  size_t off = 0;
  auto alloc = [&](size_t bytes) {
    char* ptr = ws + off;
    off = (off + bytes + 255) & ~(size_t)255;
    return ptr;
  };
  int* flag = (int*)alloc(256);
  unsigned short* qc = (unsigned short*)alloc((size_t)2048 * 1024 * 2);
  unsigned short* srcc = (unsigned short*)alloc((size_t)1024 * 1024 * 2);
  unsigned short* trgc = (unsigned short*)alloc((size_t)1024 * 1024 * 2);
  unsigned short* biasc = (unsigned short*)alloc((size_t)6 * 512 * 2);
  unsigned short* wT = (unsigned short*)alloc((size_t)5 * 524288 * 2);
  unsigned short* woT = (unsigned short*)alloc((size_t)512 * 1536 * 2);
  unsigned short* q_s = (unsigned short*)alloc((size_t)2048 * 512 * 2);
  unsigned short* s_key = (unsigned short*)alloc((size_t)1024 * 512 * 2);
  unsigned short* t_key = (unsigned short*)alloc((size_t)1024 * 512 * 2);
  unsigned short* sv_T = (unsigned short*)alloc((size_t)16 * 512 * 64 * 2);
  unsigned short* tv_T = (unsigned short*)alloc((size_t)16 * 512 * 64 * 2);
  unsigned short* scores = (unsigned short*)alloc((size_t)2048 * 4096 * 2);
  unsigned short* ctx = (unsigned short*)alloc((size_t)2048 * 512 * 2);
  unsigned short* part = (unsigned short*)alloc((size_t)4 * 2048 * 512 * 2);
  (void)ws_size; (void)in_sizes; (void)n_in; (void)out_size;

  hipLaunchKernelGGL(k_detect, dim3(1), dim3(64), 0, stream, query, flag);

  ConvArgs ca;
  ca.src[0] = query; ca.src[1] = src; ca.src[2] = trg;
  ca.src[3] = bq; ca.src[4] = bs; ca.src[5] = bt; ca.src[6] = bsv; ca.src[7] = btv; ca.src[8] = bo;
  ca.dst[0] = qc; ca.dst[1] = srcc; ca.dst[2] = trgc;
  for (int i = 0; i < 6; ++i) ca.dst[3 + i] = biasc + i * 512;
  ca.n[0] = 2048 * 1024; ca.n[1] = 1024 * 1024; ca.n[2] = 1024 * 1024;
  for (int i = 0; i < 6; ++i) ca.n[3 + i] = 512;
  hipLaunchKernelGGL(k_convert, dim3(512, 1, 9), dim3(256), 0, stream, ca, flag);

  TransArgs ta;
  ta.src[0] = Wq; ta.src[1] = Ws; ta.src[2] = Wt; ta.src[3] = Wsv; ta.src[4] = Wtv; ta.src[5] = Wo;
  for (int i = 0; i < 5; ++i) { ta.dst[i] = wT + (size_t)i * 524288; ta.K[i] = 1024; }
  ta.dst[5] = woT; ta.K[5] = 1536;
  hipLaunchKernelGGL(k_transpose, dim3(16, 48, 6), dim3(256), 0, stream, ta, flag);

  ProjArgs pa;
  pa.A[0] = qc; pa.A[1] = srcc; pa.A[2] = trgc; pa.A[3] = srcc; pa.A[4] = trgc;
  for (int i = 0; i < 5; ++i) pa.W[i] = wT + (size_t)i * 524288;
  for (int i = 0; i < 5; ++i) pa.bias[i] = biasc + i * 512;
  pa.out[0] = q_s; pa.out[1] = s_key; pa.out[2] = t_key; pa.out[3] = sv_T; pa.out[4] = tv_T;
  hipLaunchKernelGGL(k_proj, dim3(8, 32, 5), dim3(256), 0, stream, pa);

  hipLaunchKernelGGL(k_scores, dim3(32, 2, 16), dim3(256), 0, stream, q_s, s_key, t_key, scores);
  hipLaunchKernelGGL(k_softmax, dim3(2048), dim3(256), 0, stream, scores);
  hipLaunchKernelGGL(k_ctx, dim3(32, 8, 4), dim3(256), 0, stream, scores, sv_T, tv_T, part);
  hipLaunchKernelGGL(k_reduce, dim3(512), dim3(256), 0, stream, part, ctx);
  hipLaunchKernelGGL(k_out, dim3(8, 32, 1), dim3(256), 0, stream, qc, ctx, woT,
                     biasc + 5 * 512, d_out, flag);
}

// Round 7
// 224.494 us; speedup vs baseline: 1.3630x; 1.3630x over previous
//
#include <hip/hip_runtime.h>
#include <cstdint>

// ---------- types & helpers ----------
typedef __attribute__((ext_vector_type(8))) short short8_t;
typedef __attribute__((ext_vector_type(8))) __bf16 bf16x8_t;
typedef __attribute__((ext_vector_type(4))) float f32x4_t;

__device__ __forceinline__ float bf2f(unsigned short u) {
  return __uint_as_float(((unsigned)u) << 16);
}
__device__ __forceinline__ unsigned short f2bf(float f) {  // RNE
  unsigned u = __float_as_uint(f);
  u += 0x7FFFu + ((u >> 16) & 1u);
  return (unsigned short)(u >> 16);
}
__device__ __forceinline__ unsigned short f2bf_rhu(float f) {  // round-half-up (hot loops)
  return (unsigned short)((__float_as_uint(f) + 0x8000u) >> 16);
}

// MFMA wrapper: tolerate either builtin signature (short8 or bf16x8 operands).
template <typename V>
__device__ __forceinline__ auto mfma16_impl(V a, V b, f32x4_t c, int)
    -> decltype(__builtin_amdgcn_mfma_f32_16x16x32_bf16(a, b, c, 0, 0, 0)) {
  return __builtin_amdgcn_mfma_f32_16x16x32_bf16(a, b, c, 0, 0, 0);
}
template <typename V>
__device__ __forceinline__ f32x4_t mfma16_impl(V a, V b, f32x4_t c, long) {
  bf16x8_t ab = __builtin_bit_cast(bf16x8_t, a);
  bf16x8_t bb = __builtin_bit_cast(bf16x8_t, b);
  return __builtin_amdgcn_mfma_f32_16x16x32_bf16(ab, bb, c, 0, 0, 0);
}
__device__ __forceinline__ f32x4_t MFMA16(short8_t a, short8_t b, f32x4_t c) {
  return mfma16_impl(a, b, c, 0);
}

#define PITCH 40    // 64x32 tiles: high-residency small-LDS form (k_proj/k_out)
#define SPITCH 136  // 64x128 tiles (k_scores)

// Small-LDS 2-barrier GEMM block vars: 4 waves, 64x64 tile.
// NOTE: this form keeps LDS at 10 KB -> up to 8 blocks/CU residency; measured
// faster than 128-k chunk+prefetch when grid < ~4 useful blocks/CU (R6 lesson).
#define GEMM_VARS                                                       \
  __shared__ __align__(16) short Als[64 * PITCH];                       \
  __shared__ __align__(16) short Bls[64 * PITCH];                       \
  const int tid = threadIdx.x;                                          \
  const int lane = tid & 63;                                            \
  const int wv = tid >> 6;                                              \
  const int mw = (wv >> 1) << 5;                                        \
  const int nw = (wv & 1) << 5;                                         \
  const int fr = lane & 15;                                             \
  const int fq = lane >> 4;                                             \
  const int sr = tid >> 2;                                              \
  const int sc = (tid & 3) << 3;                                        \
  f32x4_t acc00 = {0.f, 0.f, 0.f, 0.f};                                 \
  f32x4_t acc01 = acc00, acc10 = acc00, acc11 = acc00;

#define MFMA_STEP()                                                     \
  do {                                                                  \
    const short* ap_ = &Als[(mw + fr) * PITCH + fq * 8];                \
    const short* bp_ = &Bls[(nw + fr) * PITCH + fq * 8];                \
    short8_t a0_ = *(const short8_t*)ap_;                               \
    short8_t a1_ = *(const short8_t*)(ap_ + 16 * PITCH);                \
    short8_t b0_ = *(const short8_t*)bp_;                               \
    short8_t b1_ = *(const short8_t*)(bp_ + 16 * PITCH);                \
    acc00 = MFMA16(a0_, b0_, acc00);                                    \
    acc01 = MFMA16(a0_, b1_, acc01);                                    \
    acc10 = MFMA16(a1_, b0_, acc10);                                    \
    acc11 = MFMA16(a1_, b1_, acc11);                                    \
  } while (0)

#define FRAG_VARS                                                       \
  const int tid = threadIdx.x;                                          \
  const int lane = tid & 63;                                            \
  const int wv = tid >> 6;                                              \
  const int mw = (wv >> 1) << 5;                                        \
  const int nw = (wv & 1) << 5;                                         \
  const int fr = lane & 15;                                             \
  const int fq = lane >> 4;                                             \
  f32x4_t acc00 = {0.f, 0.f, 0.f, 0.f};                                 \
  f32x4_t acc01 = acc00, acc10 = acc00, acc11 = acc00;

// Body sees: ml (local m), nl (local n), vv (float value). Variadic for commas.
#define GEMM_EPILOGUE(...)                                              \
  {                                                                     \
    const f32x4_t accs_[4] = {acc00, acc01, acc10, acc11};              \
    _Pragma("unroll") for (int im_ = 0; im_ < 2; ++im_)                 \
    _Pragma("unroll") for (int jn_ = 0; jn_ < 2; ++jn_) {               \
      f32x4_t aa_ = accs_[im_ * 2 + jn_];                               \
      const int ml0_ = mw + im_ * 16 + fq * 4;                          \
      const int nl = nw + jn_ * 16 + fr;                                \
      _Pragma("unroll") for (int r_ = 0; r_ < 4; ++r_) {                \
        const int ml = ml0_ + r_;                                       \
        const float vv = aa_[r_];                                       \
        __VA_ARGS__;                                                    \
      }                                                                 \
    }                                                                   \
  }

// bf16x8 (short8) * scalar f32 -> bf16x8
__device__ __forceinline__ short8_t prods8(short8_t t, float s) {
  union { short8_t v; unsigned short u[8]; } in, r;
  in.v = t;
#pragma unroll
  for (int j = 0; j < 8; ++j) r.u[j] = f2bf_rhu(bf2f(in.u[j]) * s);
  return r.v;
}

// ---------- dtype detector ----------
__global__ void k_detect(const void* q, int* flag) {
  const int t = threadIdx.x;  // 64 threads
  const unsigned short* p = (const unsigned short*)q;
  int w = 0;
  for (int i = t; i < 512; i += 64) {
    float v = bf2f(p[i]);
    float av = fabsf(v);
    if (!(av <= 1e4f) || (v != 0.f && av < 1e-10f)) ++w;  // NaN fails av<=1e4
  }
  for (int off = 32; off > 0; off >>= 1) w += __shfl_xor(w, off);
  if (t == 0) *flag = (w > 40) ? 1 : 0;  // 1 = inputs are f32
}

__device__ __forceinline__ unsigned short load_as_bf16(const void* p, size_t i, int f32mode) {
  return f32mode ? f2bf(((const float*)p)[i]) : ((const unsigned short*)p)[i];
}

// ---------- merged prep: convert (z<9) + weight transpose (z>=9) ----------
struct PrepArgs {
  const void* csrc[9];
  unsigned short* cdst[9];
  int cn[9];
  const void* tsrc[6];
  unsigned short* tdst[6];
  int tK[6];
};

__global__ __launch_bounds__(256) void k_prep(PrepArgs a, const int* flag) {
  const int z = blockIdx.z;
  const int f32mode = *flag;
  if (z < 9) {
    const int n = a.cn[z];
    const int bid = blockIdx.y * 16 + blockIdx.x;  // 0..767
    const int stride = 768 * 256;
    for (int i = bid * 256 + threadIdx.x; i < n; i += stride)
      a.cdst[z][i] = load_as_bf16(a.csrc[z], i, f32mode);
  } else {
    const int w = z - 9;
    const int K = a.tK[w];
    const int k0 = blockIdx.y * 32, n0 = blockIdx.x * 32;
    if (k0 >= K) return;
    __shared__ unsigned short t[32][33];
    const int tx = threadIdx.x & 31, ty = threadIdx.x >> 5;
    const void* s = a.tsrc[w];
#pragma unroll
    for (int i = 0; i < 4; ++i)
      t[ty + i * 8][tx] = load_as_bf16(s, (size_t)(k0 + ty + i * 8) * 512 + n0 + tx, f32mode);
    __syncthreads();
    unsigned short* d = a.tdst[w];
#pragma unroll
    for (int i = 0; i < 4; ++i)
      d[(size_t)(n0 + ty + i * 8) * K + k0 + tx] = t[tx][ty + i * 8];
  }
}

// ---------- five projections, small-LDS 2-barrier form, compact 768-block grid ----------
struct ProjArgs {
  const unsigned short* A[5];
  const unsigned short* W[5];
  const unsigned short* bias[5];
  unsigned short* out[5];
};

__global__ __launch_bounds__(256) void k_proj(ProjArgs args) {
  const int id = blockIdx.x;  // 0..767, all live
  int op, by, bx;
  if (id < 256) {
    op = 0; by = id >> 3; bx = id & 7;
  } else {
    int r = id - 256;
    op = 1 + (r >> 7); r &= 127; by = r >> 3; bx = r & 7;
  }
  const int m0 = by * 64, n0 = bx * 64;
  const unsigned short* A = args.A[op];
  const unsigned short* W = args.W[op];
  GEMM_VARS;
  for (int k0 = 0; k0 < 1024; k0 += 32) {
    uint4 av = *(const uint4*)&A[(size_t)(m0 + sr) * 1024 + k0 + sc];
    uint4 bv = *(const uint4*)&W[(size_t)(n0 + sr) * 1024 + k0 + sc];
    __syncthreads();
    *(uint4*)&Als[sr * PITCH + sc] = av;
    *(uint4*)&Bls[sr * PITCH + sc] = bv;
    __syncthreads();
    MFMA_STEP();
  }
  const float scale = (op == 0) ? 0.044194173824159216f : 1.0f;
  const unsigned short* bias = args.bias[op];
  unsigned short* out = args.out[op];
  GEMM_EPILOGUE({
    const float v = (vv + bf2f(bias[n0 + nl])) * scale;
    const int m = m0 + ml;
    const int n = n0 + nl;
    if (op < 3) {
      out[(size_t)m * 512 + n] = f2bf(v);
    } else {
      const int bb = m >> 6;
      const int ss = m & 63;
      out[(size_t)bb * 32768 + (size_t)n * 64 + ss] = f2bf(v);
    }
  });
}

// ---------- scores: reuse-heavy LDS-staged (R5 known-good) ----------
__global__ __launch_bounds__(256) void k_scores(
    const unsigned short* __restrict__ qs, const unsigned short* __restrict__ skey,
    const unsigned short* __restrict__ tkey, unsigned short* __restrict__ scores) {
  const int b = blockIdx.z;
  const int m0 = blockIdx.y * 64;
  const int sx = blockIdx.x;  // s = sx*2 + {0,1}
  const int tid = threadIdx.x;
  const int lane = tid & 63;
  const int wv = tid >> 6;
  const int mw = (wv >> 1) << 5;
  const int nw = (wv & 1) << 5;
  const int fr = lane & 15;
  const int fq = lane >> 4;
  __shared__ __align__(16) unsigned short qL[64 * SPITCH];
  __shared__ __align__(16) unsigned short tkL[64 * SPITCH];
  __shared__ __align__(16) unsigned short skL[2 * SPITCH];
  f32x4_t acc[2][4];
#pragma unroll
  for (int s = 0; s < 2; ++s)
#pragma unroll
    for (int i = 0; i < 4; ++i) acc[s][i] = (f32x4_t){0.f, 0.f, 0.f, 0.f};
  const unsigned short* qb = qs + ((size_t)b * 128 + m0) * 512;
  const unsigned short* tkb = tkey + (size_t)b * 64 * 512;
  const unsigned short* skb = skey + ((size_t)b * 64 + sx * 2) * 512;
  for (int kc = 0; kc < 4; ++kc) {
    const int kbase = kc * 128;
    __syncthreads();
#pragma unroll
    for (int i = 0; i < 4; ++i) {
      const int u = tid + i * 256;
      const int r = u >> 4, c = (u & 15) * 8;
      *(uint4*)&qL[r * SPITCH + c] = *(const uint4*)&qb[(size_t)r * 512 + kbase + c];
      *(uint4*)&tkL[r * SPITCH + c] = *(const uint4*)&tkb[(size_t)r * 512 + kbase + c];
    }
    if (tid < 32) {
      const int r = tid >> 4, c = (tid & 15) * 8;
      *(uint4*)&skL[r * SPITCH + c] = *(const uint4*)&skb[(size_t)r * 512 + kbase + c];
    }
    __syncthreads();
#pragma unroll
    for (int ks = 0; ks < 4; ++ks) {
      const int kf = ks * 32 + fq * 8;
      short8_t a0 = *(const short8_t*)&qL[(mw + fr) * SPITCH + kf];
      short8_t a1 = *(const short8_t*)&qL[(mw + 16 + fr) * SPITCH + kf];
      uint4 tq[2];
      tq[0] = *(const uint4*)&tkL[(nw + fr) * SPITCH + kf];
      tq[1] = *(const uint4*)&tkL[(nw + 16 + fr) * SPITCH + kf];
      float tlo[2][4], thi[2][4];
#pragma unroll
      for (int h = 0; h < 2; ++h) {
        const unsigned* tw = (const unsigned*)&tq[h];
#pragma unroll
        for (int j = 0; j < 4; ++j) {
          tlo[h][j] = __uint_as_float(tw[j] << 16);
          thi[h][j] = __uint_as_float(tw[j] & 0xffff0000u);
        }
      }
#pragma unroll
      for (int s = 0; s < 2; ++s) {
        uint4 skq = *(const uint4*)&skL[s * SPITCH + kf];
        const unsigned* sw = (const unsigned*)&skq;
        union { short8_t v; unsigned w[4]; } b0, b1;
#pragma unroll
        for (int j = 0; j < 4; ++j) {
          const float slo = __uint_as_float(sw[j] << 16);
          const float shi = __uint_as_float(sw[j] & 0xffff0000u);
          b0.w[j] = __builtin_amdgcn_perm(__float_as_uint(thi[0][j] * shi),
                                          __float_as_uint(tlo[0][j] * slo), 0x07060302);
          b1.w[j] = __builtin_amdgcn_perm(__float_as_uint(thi[1][j] * shi),
                                          __float_as_uint(tlo[1][j] * slo), 0x07060302);
        }
        acc[s][0] = MFMA16(a0, b0.v, acc[s][0]);
        acc[s][1] = MFMA16(a0, b1.v, acc[s][1]);
        acc[s][2] = MFMA16(a1, b0.v, acc[s][2]);
        acc[s][3] = MFMA16(a1, b1.v, acc[s][3]);
      }
    }
  }
#pragma unroll
  for (int s = 0; s < 2; ++s) {
    unsigned short* out = scores + ((size_t)b * 128 + m0) * 4096 + (size_t)(sx * 2 + s) * 64;
#pragma unroll
    for (int im = 0; im < 2; ++im)
#pragma unroll
      for (int jn = 0; jn < 2; ++jn) {
        f32x4_t aa = acc[s][im * 2 + jn];
        const int col = nw + jn * 16 + fr;
#pragma unroll
        for (int r = 0; r < 4; ++r) {
          const int row = mw + im * 16 + fq * 4 + r;
          out[(size_t)row * 4096 + col] = f2bf(aa[r]);
        }
      }
  }
}

// ---------- in-place softmax over each row of 4096 ----------
__global__ __launch_bounds__(256) void k_softmax(unsigned short* __restrict__ s) {
  unsigned short* p = s + (size_t)blockIdx.x * 4096;
  const int t = threadIdx.x;
  union U8 { uint4 q; unsigned short u[8]; };
  U8 a, b;
  a.q = *(const uint4*)&p[t * 16];
  b.q = *(const uint4*)&p[t * 16 + 8];
  float x[16];
#pragma unroll
  for (int j = 0; j < 8; ++j) { x[j] = bf2f(a.u[j]); x[8 + j] = bf2f(b.u[j]); }
  float m = x[0];
#pragma unroll
  for (int j = 1; j < 16; ++j) m = fmaxf(m, x[j]);
  for (int off = 32; off > 0; off >>= 1) m = fmaxf(m, __shfl_xor(m, off));
  __shared__ float redm[4], reds[4];
  if ((t & 63) == 0) redm[t >> 6] = m;
  __syncthreads();
  m = fmaxf(fmaxf(redm[0], redm[1]), fmaxf(redm[2], redm[3]));
  float sum = 0.f;
#pragma unroll
  for (int j = 0; j < 16; ++j) { x[j] = __expf(x[j] - m); sum += x[j]; }
  for (int off = 32; off > 0; off >>= 1) sum += __shfl_xor(sum, off);
  if ((t & 63) == 0) reds[t >> 6] = sum;
  __syncthreads();
  sum = reds[0] + reds[1] + reds[2] + reds[3];
  const float inv = 1.0f / sum;
#pragma unroll
  for (int j = 0; j < 8; ++j) {
    a.u[j] = f2bf(x[j] * inv);
    b.u[j] = f2bf(x[8 + j] * inv);
  }
  *(uint4*)&p[t * 16] = a.q;
  *(uint4*)&p[t * 16 + 8] = b.q;
}

// ---------- ctx partials: split-K x4 over s; bf16 partials ----------
__global__ __launch_bounds__(256) void k_ctx(
    const unsigned short* __restrict__ p, const unsigned short* __restrict__ svT,
    const unsigned short* __restrict__ tvT, unsigned short* __restrict__ part) {
  const int b = blockIdx.x >> 1;
  const int m0 = (blockIdx.x & 1) * 64;
  const int n0 = blockIdx.y * 64;
  const int z = blockIdx.z;
  FRAG_VARS;
  __shared__ __align__(16) unsigned short tvl[64 * 72];
  __shared__ __align__(16) unsigned short svl[64 * 24];
  {
    const unsigned short* tvb = tvT + (size_t)b * 32768 + (size_t)n0 * 64;
    const unsigned short* svb = svT + (size_t)b * 32768 + (size_t)n0 * 64 + z * 16;
#pragma unroll
    for (int it = 0; it < 2; ++it) {
      const int idx = tid + it * 256;
      const int r = idx >> 3, c = (idx & 7) * 8;
      *(uint4*)&tvl[r * 72 + c] = *(const uint4*)&tvb[(size_t)r * 64 + c];
    }
    if (tid < 128) {
      const int r = tid >> 1, c = (tid & 1) * 8;
      *(uint4*)&svl[r * 24 + c] = *(const uint4*)&svb[(size_t)r * 64 + c];
    }
  }
  __syncthreads();
  const unsigned short* ar0 =
      p + ((size_t)b * 128 + m0 + mw + fr) * 4096 + z * 1024 + fq * 8;
  const unsigned short* ar1 = ar0 + (size_t)16 * 4096;
  uint4 pa0[4], pa1[4];
#pragma unroll
  for (int i = 0; i < 4; ++i) {
    pa0[i] = *(const uint4*)(ar0 + i * 32);
    pa1[i] = *(const uint4*)(ar1 + i * 32);
  }
#pragma unroll 4
  for (int ks = 0; ks < 32; ++ks) {
    const int sl = ks & 3;
    short8_t av0 = __builtin_bit_cast(short8_t, pa0[sl]);
    short8_t av1 = __builtin_bit_cast(short8_t, pa1[sl]);
    const int kn = ks + 4;
    if (kn < 32) {
      pa0[sl] = *(const uint4*)(ar0 + kn * 32);
      pa1[sl] = *(const uint4*)(ar1 + kn * 32);
    }
    const int s_l = ks >> 1;
    const int t0 = (ks & 1) * 32;
    short8_t tv0 = *(const short8_t*)&tvl[(nw + fr) * 72 + t0 + fq * 8];
    short8_t tv1 = *(const short8_t*)&tvl[(nw + 16 + fr) * 72 + t0 + fq * 8];
    const float sv0 = bf2f(svl[(nw + fr) * 24 + s_l]);
    const float sv1 = bf2f(svl[(nw + 16 + fr) * 24 + s_l]);
    short8_t bv0 = prods8(tv0, sv0);
    short8_t bv1 = prods8(tv1, sv1);
    acc00 = MFMA16(av0, bv0, acc00);
    acc01 = MFMA16(av0, bv1, acc01);
    acc10 = MFMA16(av1, bv0, acc10);
    acc11 = MFMA16(av1, bv1, acc11);
  }
  unsigned short* out = part + ((size_t)z * 2048 + (size_t)b * 128 + m0) * 512 + n0;
  GEMM_EPILOGUE({ out[(size_t)ml * 512 + nl] = f2bf(vv); });
}

// ---------- reduce 4 bf16 partials -> bf16 ctx ----------
__global__ __launch_bounds__(256) void k_reduce(const unsigned short* __restrict__ part,
                                                unsigned short* __restrict__ ctx) {
  const size_t N = (size_t)2048 * 512;
  const size_t i = ((size_t)blockIdx.x * 256 + threadIdx.x) * 8;
  float s[8];
#pragma unroll
  for (int j = 0; j < 8; ++j) s[j] = 0.f;
#pragma unroll
  for (int z = 0; z < 4; ++z) {
    union { uint4 q; unsigned short u[8]; } t;
    t.q = *(const uint4*)&part[z * N + i];
#pragma unroll
    for (int j = 0; j < 8; ++j) s[j] += bf2f(t.u[j]);
  }
  union { uint4 q; unsigned short u[8]; } o;
#pragma unroll
  for (int j = 0; j < 8; ++j) o.u[j] = f2bf(s[j]);
  *(uint4*)&ctx[i] = o.q;
}

// ---------- out = relu(concat(query, ctx) @ Wo + bo), small-LDS form ----------
__global__ __launch_bounds__(256) void k_out(
    const unsigned short* __restrict__ query, const unsigned short* __restrict__ ctx,
    const unsigned short* __restrict__ WoT, const unsigned short* __restrict__ bo,
    void* __restrict__ outv, const int* __restrict__ flag) {
  const int m0 = blockIdx.y * 64, n0 = blockIdx.x * 64;
  const int f32mode = *flag;
  GEMM_VARS;
  for (int k0 = 0; k0 < 1536; k0 += 32) {
    uint4 av;
    if (k0 < 1024)
      av = *(const uint4*)&query[(size_t)(m0 + sr) * 1024 + k0 + sc];
    else
      av = *(const uint4*)&ctx[(size_t)(m0 + sr) * 512 + (k0 - 1024) + sc];
    uint4 bv = *(const uint4*)&WoT[(size_t)(n0 + sr) * 1536 + k0 + sc];
    __syncthreads();
    *(uint4*)&Als[sr * PITCH + sc] = av;
    *(uint4*)&Bls[sr * PITCH + sc] = bv;
    __syncthreads();
    MFMA_STEP();
  }
  GEMM_EPILOGUE({
    float v = fmaxf(vv + bf2f(bo[n0 + nl]), 0.f);
    const size_t idx = (size_t)(m0 + ml) * 512 + n0 + nl;
    if (f32mode)
      ((float*)outv)[idx] = v;
    else
      ((unsigned short*)outv)[idx] = f2bf(v);
  });
}

// ---------- launch ----------
extern "C" void kernel_launch(void* const* d_in, const int* in_sizes, int n_in,
                              void* d_out, int out_size, void* d_ws, size_t ws_size,
                              hipStream_t stream) {
  const void* query = d_in[0];
  const void* src = d_in[1];
  const void* trg = d_in[2];
  const void* Wq = d_in[3];
  const void* bq = d_in[4];
  const void* Ws = d_in[5];
  const void* bs = d_in[6];
  const void* Wt = d_in[7];
  const void* bt = d_in[8];
  const void* Wsv = d_in[9];
  const void* bsv = d_in[10];
  const void* Wtv = d_in[11];
  const void* btv = d_in[12];
  const void* Wo = d_in[13];
  const void* bo = d_in[14];

  char* ws = (char*)d_ws;
  size_t off = 0;
  auto alloc = [&](size_t bytes) {
    char* ptr = ws + off;
    off = (off + bytes + 255) & ~(size_t)255;
    return ptr;
  };
  int* flag = (int*)alloc(256);
  unsigned short* qc = (unsigned short*)alloc((size_t)2048 * 1024 * 2);
  unsigned short* srcc = (unsigned short*)alloc((size_t)1024 * 1024 * 2);
  unsigned short* trgc = (unsigned short*)alloc((size_t)1024 * 1024 * 2);
  unsigned short* biasc = (unsigned short*)alloc((size_t)6 * 512 * 2);
  unsigned short* wT = (unsigned short*)alloc((size_t)5 * 524288 * 2);
  unsigned short* woT = (unsigned short*)alloc((size_t)512 * 1536 * 2);
  unsigned short* q_s = (unsigned short*)alloc((size_t)2048 * 512 * 2);
  unsigned short* s_key = (unsigned short*)alloc((size_t)1024 * 512 * 2);
  unsigned short* t_key = (unsigned short*)alloc((size_t)1024 * 512 * 2);
  unsigned short* sv_T = (unsigned short*)alloc((size_t)16 * 512 * 64 * 2);
  unsigned short* tv_T = (unsigned short*)alloc((size_t)16 * 512 * 64 * 2);
  unsigned short* scores = (unsigned short*)alloc((size_t)2048 * 4096 * 2);
  unsigned short* ctx = (unsigned short*)alloc((size_t)2048 * 512 * 2);
  unsigned short* part = (unsigned short*)alloc((size_t)4 * 2048 * 512 * 2);
  (void)ws_size; (void)in_sizes; (void)n_in; (void)out_size;

  hipLaunchKernelGGL(k_detect, dim3(1), dim3(64), 0, stream, query, flag);

  PrepArgs pr;
  pr.csrc[0] = query; pr.csrc[1] = src; pr.csrc[2] = trg;
  pr.csrc[3] = bq; pr.csrc[4] = bs; pr.csrc[5] = bt;
  pr.csrc[6] = bsv; pr.csrc[7] = btv; pr.csrc[8] = bo;
  pr.cdst[0] = qc; pr.cdst[1] = srcc; pr.cdst[2] = trgc;
  for (int i = 0; i < 6; ++i) pr.cdst[3 + i] = biasc + i * 512;
  pr.cn[0] = 2048 * 1024; pr.cn[1] = 1024 * 1024; pr.cn[2] = 1024 * 1024;
  for (int i = 0; i < 6; ++i) pr.cn[3 + i] = 512;
  pr.tsrc[0] = Wq; pr.tsrc[1] = Ws; pr.tsrc[2] = Wt;
  pr.tsrc[3] = Wsv; pr.tsrc[4] = Wtv; pr.tsrc[5] = Wo;
  for (int i = 0; i < 5; ++i) { pr.tdst[i] = wT + (size_t)i * 524288; pr.tK[i] = 1024; }
  pr.tdst[5] = woT; pr.tK[5] = 1536;
  hipLaunchKernelGGL(k_prep, dim3(16, 48, 15), dim3(256), 0, stream, pr, flag);

  ProjArgs pa;
  pa.A[0] = qc; pa.A[1] = srcc; pa.A[2] = trgc; pa.A[3] = srcc; pa.A[4] = trgc;
  for (int i = 0; i < 5; ++i) pa.W[i] = wT + (size_t)i * 524288;
  for (int i = 0; i < 5; ++i) pa.bias[i] = biasc + i * 512;
  pa.out[0] = q_s; pa.out[1] = s_key; pa.out[2] = t_key; pa.out[3] = sv_T; pa.out[4] = tv_T;
  hipLaunchKernelGGL(k_proj, dim3(768), dim3(256), 0, stream, pa);

  hipLaunchKernelGGL(k_scores, dim3(32, 2, 16), dim3(256), 0, stream, q_s, s_key, t_key, scores);
  hipLaunchKernelGGL(k_softmax, dim3(2048), dim3(256), 0, stream, scores);
  hipLaunchKernelGGL(k_ctx, dim3(32, 8, 4), dim3(256), 0, stream, scores, sv_T, tv_T, part);
  hipLaunchKernelGGL(k_reduce, dim3(512), dim3(256), 0, stream, part, ctx);
  hipLaunchKernelGGL(k_out, dim3(8, 32, 1), dim3(256), 0, stream, qc, ctx, woT,
                     biasc + 5 * 512, d_out, flag);
}